// Round 26
// baseline (489.121 us; speedup 1.0000x reference)
//
#include <hip/hip_runtime.h>
#include <hip/hip_bf16.h>

// B=8, S=1024, D=1024, H=16, DK=DV=64. TEMPER=32.
// Contract (verified r15+): documented input order, fp32 floats, i32-or-byte mask at d3,
// d_out FLOAT32: out (8,1024,1024) then attns (128,1024,1024).
// r26: fused kernel latency fixes -- 2-deep K prefetch; V first-fragments hoisted above
// the attns-store loop (store latency covers V load latency); 2-deep V prefetch.
// Rest identical to r25.

typedef __bf16 bf16x8 __attribute__((ext_vector_type(8)));
typedef float f32x4 __attribute__((ext_vector_type(4)));

#define MFMA(a, b, c) __builtin_amdgcn_mfma_f32_16x16x32_bf16(a, b, c, 0, 0, 0)

static __device__ __forceinline__ bf16x8 ld8(const __bf16* p) {
    return *reinterpret_cast<const bf16x8*>(p);
}
static __device__ __forceinline__ bf16x8 cvt8(float4 x, float4 y) {
    bf16x8 r;
    r[0] = (__bf16)x.x; r[1] = (__bf16)x.y; r[2] = (__bf16)x.z; r[3] = (__bf16)x.w;
    r[4] = (__bf16)y.x; r[5] = (__bf16)y.y; r[6] = (__bf16)y.z; r[7] = (__bf16)y.w;
    return r;
}

// pack mask (int32 or bytes, autodetected) -> 1 bit/elem. 262144 u32 words, grid 1024.
__global__ void pack_mask_kernel(const void* mask, unsigned* mbits) {
    int l = threadIdx.x & 63;
    unsigned w0 = ((const unsigned*)mask)[l];
    int bytemask = __any(w0 > 1u) ? 1 : 0;
    int i = blockIdx.x * 256 + threadIdx.x;
    unsigned out = 0;
    if (bytemask) {
        const unsigned char* m8 = (const unsigned char*)mask + (size_t)i * 32;
#pragma unroll
        for (int bt = 0; bt < 32; ++bt)
            if (m8[bt]) out |= (1u << bt);
    } else {
        const int* m32 = (const int*)mask + (size_t)i * 32;
#pragma unroll
        for (int bt = 0; bt < 32; ++bt)
            if (m32[bt]) out |= (1u << bt);
    }
    mbits[i] = out;
}

// tiled w transpose: [h][d][kk] fp32 -> [h][kk][d] bf16. grid 768.
__global__ void transpose_w_kernel(const float* wq, const float* wk, const float* wv,
                                   __bf16* wqT, __bf16* wkT, __bf16* wvT) {
    __shared__ __bf16 tile[64][65];
    int bid = blockIdx.x;
    int m  = bid >> 8;
    int h  = (bid >> 4) & 15;
    int db = bid & 15;
    const float* in = (m == 0) ? wq : (m == 1) ? wk : wv;
    __bf16*     out = (m == 0) ? wqT : (m == 1) ? wkT : wvT;
    int t = threadIdx.x;
#pragma unroll
    for (int i = 0; i < 16; ++i) {
        int idx = i * 256 + t;
        int dd = idx >> 6, kk = idx & 63;
        tile[kk][dd] = (__bf16)in[h * 65536 + (db * 64 + dd) * 64 + kk];
    }
    __syncthreads();
#pragma unroll
    for (int i = 0; i < 16; ++i) {
        int idx = i * 256 + t;
        int kk = idx >> 6, dd = idx & 63;
        out[h * 65536 + kk * 1024 + db * 64 + dd] = tile[kk][dd];
    }
}

// All three projections in one launch. grid 1536 (3 x 512 tiles), XCD-swizzled.
__global__ __launch_bounds__(256, 4)
void proj3_kernel(const float* __restrict__ Q, const float* __restrict__ K,
                  const float* __restrict__ V, const __bf16* __restrict__ wqT,
                  const __bf16* __restrict__ wkT, const __bf16* __restrict__ wvT,
                  __bf16* __restrict__ q_s, __bf16* __restrict__ k_s,
                  __bf16* __restrict__ v_sT) {
    __shared__ __bf16 As[128][32];
    __shared__ __bf16 Bs[128][32];
    int nb = gridDim.x;
    int sb = (blockIdx.x & 7) * (nb >> 3) + (blockIdx.x >> 3);  // XCD swizzle
    int which = sb >> 9;
    int t     = sb & 511;
    const float*  X   = (which == 0) ? Q : (which == 1) ? K : V;
    const __bf16* WT  = (which == 0) ? wqT : (which == 1) ? wkT : wvT;
    __bf16*       out = (which == 0) ? q_s : (which == 1) ? k_s : v_sT;
    int mode = (which == 2) ? 1 : 0;
    int m0 = (t >> 3) * 128;
    int n0 = (t & 7) * 128;

    int tid = threadIdx.x;
    int l = tid & 63, w = tid >> 6;
    int lr = l & 15, g = l >> 4;
    int wm = w >> 1, wn = w & 1;

    int srow = tid >> 1, shalf = tid & 1;
    const float*  Ag = X  + (size_t)(m0 + srow) * 1024 + shalf * 16;
    const __bf16* Bg = WT + (size_t)(n0 + srow) * 1024 + shalf * 16;

    f32x4 acc[4][4] = {};
    float4 a0 = *(const float4*)(Ag);
    float4 a1 = *(const float4*)(Ag + 4);
    float4 a2 = *(const float4*)(Ag + 8);
    float4 a3 = *(const float4*)(Ag + 12);
    uint4  bv0 = *(const uint4*)(Bg);
    uint4  bv1 = *(const uint4*)(Bg + 8);

    for (int kt = 0; kt < 32; ++kt) {
        *(bf16x8*)(&As[srow][shalf * 16])     = cvt8(a0, a1);
        *(bf16x8*)(&As[srow][shalf * 16 + 8]) = cvt8(a2, a3);
        *(uint4*)(&Bs[srow][shalf * 16])      = bv0;
        *(uint4*)(&Bs[srow][shalf * 16 + 8])  = bv1;
        __syncthreads();
        if (kt < 31) {
            const float* An = Ag + (kt + 1) * 32;
            a0 = *(const float4*)(An);
            a1 = *(const float4*)(An + 4);
            a2 = *(const float4*)(An + 8);
            a3 = *(const float4*)(An + 12);
            bv0 = *(const uint4*)(Bg + (kt + 1) * 32);
            bv1 = *(const uint4*)(Bg + (kt + 1) * 32 + 8);
        }
        bf16x8 af[4], bfr[4];
#pragma unroll
        for (int mi = 0; mi < 4; ++mi)
            af[mi] = *(const bf16x8*)(&As[wm * 64 + mi * 16 + lr][g * 8]);
#pragma unroll
        for (int ni = 0; ni < 4; ++ni)
            bfr[ni] = *(const bf16x8*)(&Bs[wn * 64 + ni * 16 + lr][g * 8]);
#pragma unroll
        for (int mi = 0; mi < 4; ++mi)
#pragma unroll
            for (int ni = 0; ni < 4; ++ni)
                acc[mi][ni] = MFMA(af[mi], bfr[ni], acc[mi][ni]);
        __syncthreads();
    }

#pragma unroll
    for (int mi = 0; mi < 4; ++mi)
#pragma unroll
        for (int ni = 0; ni < 4; ++ni)
#pragma unroll
            for (int j = 0; j < 4; ++j) {
                int r = m0 + wm * 64 + mi * 16 + g * 4 + j;
                int n = n0 + wn * 64 + ni * 16 + lr;
                size_t o;
                if (mode == 0)
                    o = (size_t)(n >> 6) * 524288 + (size_t)(r >> 10) * 65536 +
                        (size_t)(r & 1023) * 64 + (n & 63);
                else
                    o = (size_t)(n >> 6) * 524288 + (size_t)(r >> 10) * 65536 +
                        (size_t)(n & 63) * 1024 + (r & 1023);
                out[o] = (__bf16)acc[mi][ni][j];
            }
}

// y = x(bf16 8192x1024) @ PW(fp32 [n][k])^T -> y bf16 row-major. grid 512.
__global__ __launch_bounds__(256, 4)
void gemm_out_kernel(const __bf16* __restrict__ X, const float* __restrict__ W,
                     __bf16* __restrict__ y) {
    __shared__ __bf16 As[128][32];
    __shared__ __bf16 Bs[128][32];
    int nb = gridDim.x;
    int sb = (blockIdx.x & 7) * (nb >> 3) + (blockIdx.x >> 3);  // XCD swizzle
    int m0 = (sb >> 3) * 128;
    int n0 = (sb & 7) * 128;
    int tid = threadIdx.x;
    int l = tid & 63, w = tid >> 6;
    int lr = l & 15, g = l >> 4;
    int wm = w >> 1, wn = w & 1;

    int srow = tid >> 1, shalf = tid & 1;
    const __bf16* Ag = X + (size_t)(m0 + srow) * 1024 + shalf * 16;
    const float*  Bg = W + (size_t)(n0 + srow) * 1024 + shalf * 16;

    f32x4 acc[4][4] = {};
    uint4  av0 = *(const uint4*)(Ag);
    uint4  av1 = *(const uint4*)(Ag + 8);
    float4 b0 = *(const float4*)(Bg);
    float4 b1 = *(const float4*)(Bg + 4);
    float4 b2 = *(const float4*)(Bg + 8);
    float4 b3 = *(const float4*)(Bg + 12);

    for (int kt = 0; kt < 32; ++kt) {
        *(uint4*)(&As[srow][shalf * 16])      = av0;
        *(uint4*)(&As[srow][shalf * 16 + 8])  = av1;
        *(bf16x8*)(&Bs[srow][shalf * 16])     = cvt8(b0, b1);
        *(bf16x8*)(&Bs[srow][shalf * 16 + 8]) = cvt8(b2, b3);
        __syncthreads();
        if (kt < 31) {
            av0 = *(const uint4*)(Ag + (kt + 1) * 32);
            av1 = *(const uint4*)(Ag + (kt + 1) * 32 + 8);
            const float* Bn = Bg + (kt + 1) * 32;
            b0 = *(const float4*)(Bn);
            b1 = *(const float4*)(Bn + 4);
            b2 = *(const float4*)(Bn + 8);
            b3 = *(const float4*)(Bn + 12);
        }
        bf16x8 af[4], bfr[4];
#pragma unroll
        for (int mi = 0; mi < 4; ++mi)
            af[mi] = *(const bf16x8*)(&As[wm * 64 + mi * 16 + lr][g * 8]);
#pragma unroll
        for (int ni = 0; ni < 4; ++ni)
            bfr[ni] = *(const bf16x8*)(&Bs[wn * 64 + ni * 16 + lr][g * 8]);
#pragma unroll
        for (int mi = 0; mi < 4; ++mi)
#pragma unroll
            for (int ni = 0; ni < 4; ++ni)
                acc[mi][ni] = MFMA(af[mi], bfr[ni], acc[mi][ni]);
        __syncthreads();
    }

#pragma unroll
    for (int mi = 0; mi < 4; ++mi)
#pragma unroll
        for (int ni = 0; ni < 4; ++ni)
#pragma unroll
            for (int j = 0; j < 4; ++j) {
                int r = m0 + wm * 64 + mi * 16 + g * 4 + j;
                int n = n0 + wn * 64 + ni * 16 + lr;
                y[(size_t)r * 1024 + n] = (__bf16)acc[mi][ni][j];
            }
}

// Fused scores+softmax+attns+PV, 32-row q-tile. grid 32*nhb (divisible by 8), XCD-swizzled.
__global__ __launch_bounds__(256, 2)
void fused_attn_kernel(const __bf16* __restrict__ qsb, const __bf16* __restrict__ ksb,
                       const __bf16* __restrict__ vsb, size_t stride, int hb0,
                       const unsigned* __restrict__ mbits,
                       float* __restrict__ attnF, __bf16* __restrict__ x) {
    __shared__ __bf16 P[32][1040];           // 66.6 KB; row stride 8 banks -> conflict-free
    __shared__ float redm[4][32], reds[4][32];
    __shared__ unsigned mb[32][32];          // 4 KB

    int nb = gridDim.x;
    int sb = (blockIdx.x & 7) * (nb >> 3) + (blockIdx.x >> 3);  // XCD swizzle
    int rel = sb >> 5;
    int q0  = (sb & 31) * 32;
    int hb  = hb0 + rel;
    int tid = threadIdx.x;
    int l = tid & 63, w = tid >> 6;
    int lr = l & 15, g = l >> 4;
    int b = hb & 7;

#pragma unroll
    for (int i = 0; i < 4; ++i) {
        int idx = i * 256 + tid;
        mb[idx >> 5][idx & 31] = mbits[((size_t)b * 1024 + q0 + (idx >> 5)) * 32 + (idx & 31)];
    }

    const __bf16* qb = qsb + rel * stride + (size_t)q0 * 64;
    const __bf16* ks = ksb + rel * stride;
    bf16x8 aQ[2][2];
#pragma unroll
    for (int rh = 0; rh < 2; ++rh) {
        aQ[rh][0] = ld8(qb + (size_t)(rh * 16 + lr) * 64 + g * 8);
        aQ[rh][1] = ld8(qb + (size_t)(rh * 16 + lr) * 64 + 32 + g * 8);
    }
    __syncthreads();

    // QK^T with 2-deep K prefetch; two row-halves share each K fragment
    const __bf16* kbase = ks + (size_t)(w * 256 + lr) * 64 + g * 8;
    bf16x8 kA0 = ld8(kbase);
    bf16x8 kB0 = ld8(kbase + 32);
    bf16x8 kA1 = ld8(kbase + 1024);          // kt=1: +16*64 elems
    bf16x8 kB1 = ld8(kbase + 1024 + 32);
    float s_lo[16][4], s_hi[16][4];
    float mx_lo[4] = {-INFINITY, -INFINITY, -INFINITY, -INFINITY};
    float mx_hi[4] = {-INFINITY, -INFINITY, -INFINITY, -INFINITY};
#pragma unroll
    for (int kt = 0; kt < 16; ++kt) {
        bf16x8 curA = (kt & 1) ? kA1 : kA0;
        bf16x8 curB = (kt & 1) ? kB1 : kB0;
        if (kt < 14) {
            const __bf16* bpn = kbase + (size_t)(kt + 2) * 1024;
            if (kt & 1) { kA1 = ld8(bpn); kB1 = ld8(bpn + 32); }
            else        { kA0 = ld8(bpn); kB0 = ld8(bpn + 32); }
        }
        f32x4 accl = {}, acch = {};
        accl = MFMA(aQ[0][0], curA, accl);
        accl = MFMA(aQ[0][1], curB, accl);
        acch = MFMA(aQ[1][0], curA, acch);
        acch = MFMA(aQ[1][1], curB, acch);
#pragma unroll
        for (int j = 0; j < 4; ++j) {
            unsigned wl = mb[g * 4 + j][w * 8 + (kt >> 1)];
            unsigned wh = mb[16 + g * 4 + j][w * 8 + (kt >> 1)];
            int sh = (kt & 1) * 16 + lr;
            float vl = ((wl >> sh) & 1u) ? -INFINITY : accl[j] * 0.03125f;
            float vh = ((wh >> sh) & 1u) ? -INFINITY : acch[j] * 0.03125f;
            s_lo[kt][j] = vl;
            s_hi[kt][j] = vh;
            mx_lo[j] = fmaxf(mx_lo[j], vl);
            mx_hi[j] = fmaxf(mx_hi[j], vh);
        }
    }
#pragma unroll
    for (int j = 0; j < 4; ++j) {
#pragma unroll
        for (int o = 8; o >= 1; o >>= 1) {
            mx_lo[j] = fmaxf(mx_lo[j], __shfl_xor(mx_lo[j], o));
            mx_hi[j] = fmaxf(mx_hi[j], __shfl_xor(mx_hi[j], o));
        }
    }
    if (lr == 0) {
#pragma unroll
        for (int j = 0; j < 4; ++j) {
            redm[w][g * 4 + j]      = mx_lo[j];
            redm[w][16 + g * 4 + j] = mx_hi[j];
        }
    }
    __syncthreads();
#pragma unroll
    for (int j = 0; j < 4; ++j) {
        int rl = g * 4 + j, rh = 16 + g * 4 + j;
        mx_lo[j] = fmaxf(fmaxf(redm[0][rl], redm[1][rl]), fmaxf(redm[2][rl], redm[3][rl]));
        mx_hi[j] = fmaxf(fmaxf(redm[0][rh], redm[1][rh]), fmaxf(redm[2][rh], redm[3][rh]));
    }

    float sum_lo[4] = {0.f, 0.f, 0.f, 0.f}, sum_hi[4] = {0.f, 0.f, 0.f, 0.f};
#pragma unroll
    for (int j = 0; j < 4; ++j) {
        int rl = g * 4 + j, rh = 16 + g * 4 + j;
        float ml = (mx_lo[j] == -INFINITY) ? 0.f : mx_lo[j];
        float mh = (mx_hi[j] == -INFINITY) ? 0.f : mx_hi[j];
#pragma unroll
        for (int kt = 0; kt < 16; ++kt) {
            int col = w * 256 + kt * 16 + lr;
            float vl = s_lo[kt][j];
            float vh = s_hi[kt][j];
            float el = (vl == -INFINITY) ? 0.f : __expf(vl - ml);
            float eh = (vh == -INFINITY) ? 0.f : __expf(vh - mh);
            sum_lo[j] += el;
            sum_hi[j] += eh;
            P[rl][col] = (__bf16)el;
            P[rh][col] = (__bf16)eh;
        }
    }
#pragma unroll
    for (int j = 0; j < 4; ++j) {
#pragma unroll
        for (int o = 8; o >= 1; o >>= 1) {
            sum_lo[j] += __shfl_xor(sum_lo[j], o);
            sum_hi[j] += __shfl_xor(sum_hi[j], o);
        }
    }
    if (lr == 0) {
#pragma unroll
        for (int j = 0; j < 4; ++j) {
            reds[w][g * 4 + j]      = sum_lo[j];
            reds[w][16 + g * 4 + j] = sum_hi[j];
        }
    }
    __syncthreads();

    // Hoist first V fragments: their latency hides under the attns-store loop below.
    const __bf16* vrow = vsb + rel * stride + (size_t)(w * 16 + lr) * 1024 + g * 8;
    bf16x8 v0 = ld8(vrow);
    bf16x8 v1 = ld8(vrow + 32);

    // coalesced nontemporal attns write (32 rows)
    float* abase = attnF + (size_t)hb * 1048576 + (size_t)q0 * 1024;
#pragma unroll
    for (int i = 0; i < 16; ++i) {
        int idx = i * 256 + tid;
        int row = idx >> 7;
        int c8  = (idx & 127) * 8;
        float tot  = reds[0][row] + reds[1][row] + reds[2][row] + reds[3][row];
        float mrow = fmaxf(fmaxf(redm[0][row], redm[1][row]),
                           fmaxf(redm[2][row], redm[3][row]));
        float inv = (mrow == -INFINITY) ? 0.f : 1.0f / tot;
        bf16x8 pv = *reinterpret_cast<const bf16x8*>(&P[row][c8]);
        f32x4 f0 = {(float)pv[0] * inv, (float)pv[1] * inv,
                    (float)pv[2] * inv, (float)pv[3] * inv};
        f32x4 f1 = {(float)pv[4] * inv, (float)pv[5] * inv,
                    (float)pv[6] * inv, (float)pv[7] * inv};
        float* dst = abase + (size_t)row * 1024 + c8;
        __builtin_nontemporal_store(f0, reinterpret_cast<f32x4*>(dst));
        __builtin_nontemporal_store(f1, reinterpret_cast<f32x4*>(dst + 4));
    }

    // PV with 2-deep V prefetch; V fragment shared by both row-halves
    f32x4 acc2l = {}, acc2h = {};
    for (int kb = 0; kb < 32; ++kb) {
        bf16x8 cur = (kb & 1) ? v1 : v0;
        if (kb < 30) {
            if (kb & 1) v1 = ld8(vrow + (kb + 2) * 32);
            else        v0 = ld8(vrow + (kb + 2) * 32);
        }
        bf16x8 pal = *reinterpret_cast<const bf16x8*>(&P[lr][kb * 32 + g * 8]);
        bf16x8 pah = *reinterpret_cast<const bf16x8*>(&P[16 + lr][kb * 32 + g * 8]);
        acc2l = MFMA(pal, cur, acc2l);
        acc2h = MFMA(pah, cur, acc2h);
    }
    int h = hb >> 3;
#pragma unroll
    for (int j = 0; j < 4; ++j) {
        int rl = g * 4 + j, rh = 16 + g * 4 + j;
        float totl = reds[0][rl] + reds[1][rl] + reds[2][rl] + reds[3][rl];
        float toth = reds[0][rh] + reds[1][rh] + reds[2][rh] + reds[3][rh];
        float ml = fmaxf(fmaxf(redm[0][rl], redm[1][rl]), fmaxf(redm[2][rl], redm[3][rl]));
        float mh = fmaxf(fmaxf(redm[0][rh], redm[1][rh]), fmaxf(redm[2][rh], redm[3][rh]));
        float invl = (ml == -INFINITY) ? 0.f : 1.0f / totl;
        float invh = (mh == -INFINITY) ? 0.f : 1.0f / toth;
        int vv = w * 16 + lr;
        x[(size_t)b * 1048576 + (size_t)(q0 + rl) * 1024 + h * 64 + vv] = (__bf16)(acc2l[j] * invl);
        x[(size_t)b * 1048576 + (size_t)(q0 + rh) * 1024 + h * 64 + vv] = (__bf16)(acc2h[j] * invh);
    }
}

// copy q_s/k_s/v_sT tail slices (hb 116..127) into reloc buffer
__global__ void reloc_kernel(const __bf16* qs, const __bf16* ks, const __bf16* vs,
                             __bf16* rel) {
    int i = blockIdx.x * 256 + threadIdx.x;  // uint4 units: 12*3*8192 = 294912
    if (i >= 294912) return;
    int hbi = i / 24576;
    int r   = i % 24576;
    int t   = r / 8192, j = r % 8192;
    const __bf16* src = ((t == 0) ? qs : (t == 1) ? ks : vs) + (size_t)(116 + hbi) * 65536;
    __bf16* dst = rel + (size_t)hbi * 196608 + t * 65536;
    reinterpret_cast<uint4*>(dst)[j] = reinterpret_cast<const uint4*>(src)[j];
}

// out fp32 rows [row0, row0+16*grid) = LN(y + pb + q)*lg + lb. No LDS; 16 rows/block.
__global__ __launch_bounds__(256, 4)
void ln_kernel(const __bf16* __restrict__ y, const float* __restrict__ pb,
               const float* __restrict__ q, const float* __restrict__ lg,
               const float* __restrict__ lb, float* __restrict__ out, int row0) {
    int tid = threadIdx.x;
    int row = tid >> 4, j16 = tid & 15;
    size_t r = (size_t)row0 + blockIdx.x * 16 + row;
    int c0 = j16 * 64;

    float v[64];
    float s1 = 0.f, s2 = 0.f;
#pragma unroll
    for (int i = 0; i < 8; ++i) {
        bf16x8 yv = ld8(y + r * 1024 + c0 + i * 8);
        float4 q0v = *(const float4*)(q + r * 1024 + c0 + i * 8);
        float4 q1v = *(const float4*)(q + r * 1024 + c0 + i * 8 + 4);
        float4 p0v = *(const float4*)(pb + c0 + i * 8);
        float4 p1v = *(const float4*)(pb + c0 + i * 8 + 4);
        float t0 = (float)yv[0] + p0v.x + q0v.x;
        float t1 = (float)yv[1] + p0v.y + q0v.y;
        float t2 = (float)yv[2] + p0v.z + q0v.z;
        float t3 = (float)yv[3] + p0v.w + q0v.w;
        float t4 = (float)yv[4] + p1v.x + q1v.x;
        float t5 = (float)yv[5] + p1v.y + q1v.y;
        float t6 = (float)yv[6] + p1v.z + q1v.z;
        float t7 = (float)yv[7] + p1v.w + q1v.w;
        v[i * 8 + 0] = t0; v[i * 8 + 1] = t1; v[i * 8 + 2] = t2; v[i * 8 + 3] = t3;
        v[i * 8 + 4] = t4; v[i * 8 + 5] = t5; v[i * 8 + 6] = t6; v[i * 8 + 7] = t7;
        s1 += t0 + t1 + t2 + t3 + t4 + t5 + t6 + t7;
        s2 += t0 * t0 + t1 * t1 + t2 * t2 + t3 * t3 + t4 * t4 + t5 * t5 + t6 * t6 + t7 * t7;
    }
#pragma unroll
    for (int m = 8; m >= 1; m >>= 1) {
        s1 += __shfl_xor(s1, m);
        s2 += __shfl_xor(s2, m);
    }
    float mu  = s1 * (1.0f / 1024.0f);
    float var = fmaxf(s2 * (1.0f / 1024.0f) - mu * mu, 0.f);
    float rs  = rsqrtf(var + 1e-5f);
#pragma unroll
    for (int i = 0; i < 16; ++i) {
        int c = c0 + i * 4;
        float4 gv = *(const float4*)(lg + c);
        float4 bv = *(const float4*)(lb + c);
        float4 o;
        o.x = (v[i * 4 + 0] - mu) * rs * gv.x + bv.x;
        o.y = (v[i * 4 + 1] - mu) * rs * gv.y + bv.y;
        o.z = (v[i * 4 + 2] - mu) * rs * gv.z + bv.z;
        o.w = (v[i * 4 + 3] - mu) * rs * gv.w + bv.w;
        *(float4*)(out + r * 1024 + c) = o;
    }
}

extern "C" void kernel_launch(void* const* d_in, const int* in_sizes, int n_in,
                              void* d_out, int out_size, void* d_ws, size_t ws_size,
                              hipStream_t stream) {
    const float* Q  = (const float*)d_in[0];
    const float* K  = (const float*)d_in[1];
    const float* V  = (const float*)d_in[2];
    const void*  M  = d_in[3];
    const float* WQ = (const float*)d_in[4];
    const float* WK = (const float*)d_in[5];
    const float* WV = (const float*)d_in[6];
    const float* PW = (const float*)d_in[7];
    const float* PB = (const float*)d_in[8];
    const float* LG = (const float*)d_in[9];
    const float* LB = (const float*)d_in[10];

    float* outF  = (float*)d_out;           // 8,388,608 fp32
    float* attnF = outF + 8388608;          // 134,217,728 fp32

    unsigned* mbits = (unsigned*)(outF + 5505024);   // out bytes [22MB,23MB), dead after fused
    __bf16*   y     = (__bf16*)(outF + 4194304);     // default: out bytes [16.7MB,33.5MB)
    bool y_in_ws = false;

    pack_mask_kernel<<<1024, 256, 0, stream>>>(M, mbits);

    __bf16* x;
    if (ws_size >= (size_t)73400320) {
        // ---------- Path A: intermediates in d_ws ----------
        char* ws = (char*)d_ws;
        __bf16* wqT  = (__bf16*)ws;                        // 2 MB
        __bf16* wkT  = (__bf16*)(ws + 2097152);            // 2 MB
        __bf16* wvT  = (__bf16*)(ws + 4194304);            // 2 MB
        __bf16* q_s  = (__bf16*)(ws + 6291456);            // 16 MB [hb][s][kk]
        __bf16* k_s  = (__bf16*)(ws + 23068672);           // 16 MB
        __bf16* v_sT = (__bf16*)(ws + 39845888);           // 16 MB [hb][vv][s]
        x            = (__bf16*)(ws + 56623104);           // 16 MB [b][s][h*64+vv]
        if (ws_size >= (size_t)90177536) {                 // +16 MB for y
            y = (__bf16*)(ws + 73400320);
            y_in_ws = true;
        }

        transpose_w_kernel<<<768, 256, 0, stream>>>(WQ, WK, WV, wqT, wkT, wvT);
        proj3_kernel<<<1536, 256, 0, stream>>>(Q, K, V, wqT, wkT, wvT, q_s, k_s, v_sT);
        fused_attn_kernel<<<4096, 256, 0, stream>>>(q_s, k_s, v_sT, (size_t)65536, 0,
                                                    mbits, attnF, x);
    } else {
        // ---------- Path B: scratch carved from d_out ----------
        __bf16* wqT  = (__bf16*)attnF;                            // chunk 0
        __bf16* wkT  = (__bf16*)(attnF + 1048576);                // chunk 1
        __bf16* wvT  = (__bf16*)(attnF + 2097152);                // chunk 2
        __bf16* q_s  = (__bf16*)(attnF + (size_t)116 * 1048576);  // chunks 116-119
        __bf16* k_s  = q_s + 8388608;                             // chunks 120-123
        __bf16* v_sT = k_s + 8388608;                             // chunks 124-127
        x            = (__bf16*)outF;                     // out bytes [0, 16.7M)
        __bf16* rel  = (__bf16*)(outF + 4194304);         // out bytes [16.7M, 21.5M)

        transpose_w_kernel<<<768, 256, 0, stream>>>(WQ, WK, WV, wqT, wkT, wvT);
        proj3_kernel<<<1536, 256, 0, stream>>>(Q, K, V, wqT, wkT, wvT, q_s, k_s, v_sT);
        fused_attn_kernel<<<32 * 116, 256, 0, stream>>>(q_s, k_s, v_sT, (size_t)65536, 0,
                                                        mbits, attnF, x);
        reloc_kernel<<<1152, 256, 0, stream>>>(q_s, k_s, v_sT, rel);
        fused_attn_kernel<<<32 * 12, 256, 0, stream>>>(rel, rel + 65536, rel + 131072,
                                                       (size_t)196608, 116, mbits, attnF, x);
    }

    // out-projection GEMM -> y
    gemm_out_kernel<<<512, 256, 0, stream>>>(x, PW, y);

    if (y_in_ws) {
        ln_kernel<<<512, 256, 0, stream>>>(y, PB, Q, LG, LB, outF, 0);
    } else {
        static const int PH[11] = {0, 4096, 6144, 7168, 7680, 7936, 8064, 8128, 8160, 8176, 8192};
        for (int p = 0; p < 10; ++p) {
            int r0 = PH[p], r1 = PH[p + 1];
            ln_kernel<<<(r1 - r0) / 16, 256, 0, stream>>>(y, PB, Q, LG, LB, outF, r0);
        }
    }
}